// Round 9
// baseline (195.668 us; speedup 1.0000x reference)
//
#include <hip/hip_runtime.h>
#include <math.h>

#define W 480
#define HT 480
#define HW (W*HT)
#define NT (HW/256)     // 900 tiles of 256
#define PP 225
#define NPATCH 1024
#define EQCAP 8192

struct State {
  unsigned slotP[4];        // resolved 16-bit bucket + misc
  unsigned slotK[4];        // remaining rank
  float sumA[3];
  unsigned eqCount;
  float A[3];
  unsigned tminbits;        // percentile result (float bits)
  unsigned eqIdx[EQCAP];
  unsigned short eqVal[EQCAP];   // low-16 dc bits, written at gather time
  float tp1[NPATCH];
  float tp2[NPATCH];
};

// ---------- radix-select resolve: wave-0 scan, 2 barriers ----------
// Integer-exact match of the original 256-wide Hillis-Steele version:
// exactly one post-mapping position p has cum_excl < k_in <= cum_incl.
__device__ __forceinline__ void resolve_level(const unsigned* __restrict__ h,
                                              unsigned k_in, int desc,
                                              unsigned* lds,
                                              unsigned& chosen, unsigned& k_out) {
  int t = threadIdx.x;
  if (t < 64) {
    int p0 = 4 * t;
    unsigned c0 = h[desc ? (255 - (p0 + 0)) : (p0 + 0)];
    unsigned c1 = h[desc ? (255 - (p0 + 1)) : (p0 + 1)];
    unsigned c2 = h[desc ? (255 - (p0 + 2)) : (p0 + 2)];
    unsigned c3 = h[desc ? (255 - (p0 + 3)) : (p0 + 3)];
    unsigned s0 = c0, s1 = s0 + c1, s2 = s1 + c2, s3 = s2 + c3;   // lane-local incl
    unsigned incl = s3;
    for (int d = 1; d < 64; d <<= 1) {          // wave inclusive scan, no barriers
      unsigned u = __shfl_up(incl, d, 64);
      if (t >= d) incl += u;
    }
    unsigned lexcl = incl - s3;                  // exclusive prefix of this lane
    unsigned i0 = lexcl + s0, i1 = lexcl + s1, i2 = lexcl + s2, i3 = lexcl + s3;
    unsigned e0 = i0 - c0, e1 = i1 - c1, e2 = i2 - c2, e3 = i3 - c3;
    if (i0 >= k_in && e0 < k_in) { lds[256] = (unsigned)(p0 + 0); lds[257] = k_in - e0; }
    if (i1 >= k_in && e1 < k_in) { lds[256] = (unsigned)(p0 + 1); lds[257] = k_in - e1; }
    if (i2 >= k_in && e2 < k_in) { lds[256] = (unsigned)(p0 + 2); lds[257] = k_in - e2; }
    if (i3 >= k_in && e3 < k_in) { lds[256] = (unsigned)(p0 + 3); lds[257] = k_in - e3; }
  }
  __syncthreads();
  unsigned p = lds[256];
  k_out = lds[257];
  chosen = desc ? (255u - p) : p;
  __syncthreads();          // keep lds[256/257] stable until all have read
}

__device__ __forceinline__ float wred_sum(float v) { for (int m = 32; m; m >>= 1) v += __shfl_xor(v, m, 64); return v; }
__device__ __forceinline__ float wred_max(float v) { for (int m = 32; m; m >>= 1) v = fmaxf(v, __shfl_xor(v, m, 64)); return v; }
__device__ __forceinline__ float wred_min(float v) { for (int m = 32; m; m >>= 1) v = fminf(v, __shfl_xor(v, m, 64)); return v; }

// ---------- 1: init + channel-min + horizontal 55-min (one row per block) ----------
__global__ __launch_bounds__(512) void k_rowmin(const float* __restrict__ img,
                                                float* __restrict__ rowmin,
                                                State* st, unsigned* __restrict__ hist16) {
  __shared__ float l[534];
  int y = blockIdx.x, t = threadIdx.x;
  int g = y * 512 + t;
  if (g < 65536) hist16[g] = 0u;               // zero the 64K-bin histogram
  for (int i = t; i < 534; i += 512) {
    int col = i - 27;
    float v = 1.0f;                              // pad value (constant_values=1.0)
    if ((unsigned)col < (unsigned)W) {
      int q = y * W + col;
      v = fminf(fminf(img[q], img[HW + q]), img[2 * HW + q]);
    }
    l[i] = v;
  }
  if (g == 0) { st->sumA[0] = 0.f; st->sumA[1] = 0.f; st->sumA[2] = 0.f; st->eqCount = 0u; }
  __syncthreads();
  if (t < W) {
    float m = l[t];
    for (int d = 1; d < 55; ++d) m = fminf(m, l[t + d]);
    rowmin[y * W + t] = m;
  }
}

// ---------- 2: vertical 55-min + 16-bit histogram with per-WAVE dedup ----------
__global__ __launch_bounds__(256) void k_minV3(const float* __restrict__ rowmin,
                                               float* __restrict__ dc,
                                               unsigned* __restrict__ hist16) {
  __shared__ unsigned short bs[256];
  int t = threadIdx.x;
  int p = blockIdx.x * 256 + t;
  int y = p / W, x = p - y * W;
  int lo = y - 27, hi = y + 27;
  float m = (lo < 0 || hi >= HT) ? 1.0f : INFINITY;
  int lo2 = max(lo, 0), hi2 = min(hi, HT - 1);
  for (int yy = lo2; yy <= hi2; ++yy) m = fminf(m, rowmin[yy * W + x]);
  dc[p] = m;
  unsigned b16 = __float_as_uint(m) >> 16;
  bs[t] = (unsigned short)b16;
  __syncthreads();
  // wave-local dedup (64-entry scan instead of 256): each pixel still counted
  // exactly once; first lane in the wave holding a distinct bucket emits it
  int base = t & ~63, rel = t & 63;
  int first = 64, cnt = 0;
  for (int j = 0; j < 64; ++j) {
    if ((unsigned)bs[base + j] == b16) { ++cnt; if (j < first) first = j; }
  }
  if (first == rel) atomicAdd(&hist16[b16], (unsigned)cnt);
}

// ---------- 3: resolve prologue (replicated) + gather sums + eq candidates ----------
__global__ __launch_bounds__(256) void k_gather2(const float* __restrict__ dc,
                                                 const float* __restrict__ img,
                                                 const unsigned* __restrict__ hist16,
                                                 State* st) {
  __shared__ unsigned lds[258];
  __shared__ unsigned lh[256];
  __shared__ float ls[3];
  __shared__ unsigned lcnt, lbase;
  int t = threadIdx.x;
  if (t == 0) { ls[0] = 0.f; ls[1] = 0.f; ls[2] = 0.f; lcnt = 0u; }
  // --- replicated resolve of the 230th-largest 16-bit bucket (read-only, deterministic) ---
  {
    const uint4* h4 = (const uint4*)hist16;
    unsigned s = 0;
    for (int i = 0; i < 64; ++i) { uint4 v = h4[t * 64 + i]; s += v.x + v.y + v.z + v.w; }
    lh[t] = s;
  }
  __syncthreads();
  unsigned ct, kc;
  resolve_level(lh, 230u, 1, lds, ct, kc);      // which 256-bin chunk
  lh[t] = hist16[ct * 256 + t];
  __syncthreads();
  unsigned b, kp;
  resolve_level(lh, kc, 1, lds, b, kp);         // which bin within chunk
  unsigned p16 = (ct << 8) | b;
  if (blockIdx.x == 0 && t == 0) { st->slotP[0] = p16; st->slotK[0] = kp; }  // for finalize
  // --- gather ---
  int p = blockIdx.x * 256 + t;
  unsigned bits = __float_as_uint(dc[p]);
  unsigned b16 = bits >> 16;
  bool eq = (b16 == p16);
  unsigned my = 0;
  if (b16 > p16) {
    atomicAdd(&ls[0], img[p]);
    atomicAdd(&ls[1], img[HW + p]);
    atomicAdd(&ls[2], img[2 * HW + p]);
  } else if (eq) {
    my = atomicAdd(&lcnt, 1u);                  // LDS atomic: cheap
  }
  __syncthreads();
  if (t == 0 && lcnt) lbase = atomicAdd(&st->eqCount, lcnt);   // one global atomic/block
  __syncthreads();
  if (eq) {
    unsigned pos = lbase + my;
    if (pos < (unsigned)EQCAP) {
      st->eqIdx[pos] = (unsigned)p;
      st->eqVal[pos] = (unsigned short)(bits & 0xFFFFu);   // save finalize's random gather
    }
  }
  if (t == 0 && (ls[0] != 0.f || ls[1] != 0.f || ls[2] != 0.f)) {
    atomicAdd(&st->sumA[0], ls[0]);
    atomicAdd(&st->sumA[1], ls[1]);
    atomicAdd(&st->sumA[2], ls[2]);
  }
}

// ---------- 4: exact select among equal-bucket: value desc (2 levels), idx asc (3) ----------
__global__ __launch_bounds__(256) void k_finalizeA2(const float* __restrict__ img, State* st) {
  __shared__ unsigned lds[258];
  __shared__ unsigned lh[256];
  __shared__ unsigned sIdx[EQCAP];
  __shared__ unsigned short sVal[EQCAP];
  __shared__ float ssum[3];
  int t = threadIdx.x;
  unsigned k = st->slotK[0];
  unsigned ne = st->eqCount; if (ne > (unsigned)EQCAP) ne = EQCAP;
  for (int i = t; i < (int)ne; i += 256) {       // both streams coalesced
    sIdx[i] = st->eqIdx[i];
    sVal[i] = st->eqVal[i];
  }
  if (t < 3) ssum[t] = 0.f;
  __syncthreads();
  // value select, descending, low-16 bits in 2 byte levels
  unsigned vpfx = 0u;
  for (int lev = 0; lev < 2; ++lev) {
    int s = 8 - 8 * lev;
    lh[t] = 0u;
    __syncthreads();
    for (int i = t; i < (int)ne; i += 256) {
      unsigned v = (unsigned)sVal[i];
      if (lev == 0 || (v >> 8) == (vpfx >> 8))
        atomicAdd(&lh[(v >> s) & 0xFFu], 1u);
    }
    __syncthreads();
    unsigned ch, kn;
    resolve_level(lh, k, 1, lds, ch, kn);
    vpfx |= ch << s;
    k = kn;
  }
  // index select ascending among exact value ties (idx < 2^18: 3 byte levels)
  unsigned pfx = 0u;
  for (int lev = 0; lev < 3; ++lev) {
    int s = 16 - 8 * lev;
    lh[t] = 0u;
    __syncthreads();
    for (int i = t; i < (int)ne; i += 256) {
      if ((unsigned)sVal[i] == vpfx) {
        unsigned v = sIdx[i];
        if ((v >> (s + 8)) == (pfx >> (s + 8)))
          atomicAdd(&lh[(v >> s) & 0xFFu], 1u);
      }
    }
    __syncthreads();
    unsigned ch, kn;
    resolve_level(lh, k, 0, lds, ch, kn);
    pfx |= ch << s;
    k = kn;
  }
  // selected: value > vpfx, or value == vpfx and idx <= pfx
  float a0 = 0.f, a1 = 0.f, a2 = 0.f;
  for (int i = t; i < (int)ne; i += 256) {
    unsigned v = (unsigned)sVal[i], q = sIdx[i];
    if (v > vpfx || (v == vpfx && q <= pfx)) {
      a0 += img[q]; a1 += img[HW + q]; a2 += img[2 * HW + q];
    }
  }
  atomicAdd(&ssum[0], a0); atomicAdd(&ssum[1], a1); atomicAdd(&ssum[2], a2);
  __syncthreads();
  if (t == 0) {
    st->A[0] = (st->sumA[0] + ssum[0]) / 230.0f;
    st->A[1] = (st->sumA[1] + ssum[1]) / 230.0f;
    st->A[2] = (st->sumA[2] + ssum[2]) / 230.0f;
  }
}

// pair test: slope in (-1,0)  <=>  dY*D < 0  AND  |dY| < |D|
// fp32-boolean-identical single-expression form: dY*(dY+D) < 0 (verified R7/R8)
__device__ __forceinline__ int slptest(float xi, float yi, float ox, float oy) {
  float dY = yi - oy;
  float D = (xi - ox) + 1e-8f;
  return (dY * (dY + D) < 0.0f) ? 1 : 0;
}

// ---------- 5: patch grids (SV inline) + bccr To+H-maxpool per row ----------
__global__ __launch_bounds__(256) void k_mega1(const float* __restrict__ img,
                                               float* __restrict__ mh, State* st) {
  __shared__ __align__(16) float2 XY[PP + 1];
  __shared__ float part[4][8];
  __shared__ float Tl[494];
  int b = blockIdx.x;
  int t = threadIdx.x;
  float A0 = st->A[0], A1 = st->A[1], A2 = st->A[2];
  const float c20 = (float)(20.0 / 255.0);
  const float c300 = (float)(300.0 / 255.0);
  if (b >= 2048) {   // bccr: compute To inline for one row, 15-tap horizontal max (pad 0)
    int y = b - 2048;
    for (int i = t; i < 494; i += 256) {
      int col = i - 7;
      float v = 0.0f;
      if ((unsigned)col < (unsigned)W) {
        int q = y * W + col;
        float r = img[q], g = img[HW + q], bl = img[2 * HW + q];
        float t0 = fmaxf((A0 - r) / (A0 - c20), (A0 - r) / (A0 - c300));
        float t1 = fmaxf((A1 - g) / (A1 - c20), (A1 - g) / (A1 - c300));
        float t2 = fmaxf((A2 - bl) / (A2 - c20), (A2 - bl) / (A2 - c300));
        v = fmaxf(fmaxf(t0, t1), t2);
      }
      Tl[i] = v;
    }
    __syncthreads();
    for (int x = t; x < W; x += 256) {
      float m = -INFINITY;
      for (int d = 0; d < 15; ++d) m = fmaxf(m, Tl[x + d]);
      mh[y * W + x] = m;
    }
    return;
  }
  int mode = b >> 10;              // 0: t1 grid, 1: shifted t2 grid
  int pid = b & 1023;
  int ph = pid >> 5, pw = pid & 31;
  if (t < PP) {
    int r = t / 15, c = t - (t / 15) * 15;
    int y, x;
    if (mode == 0) { y = ph * 15 + r; x = pw * 15 + c; }
    else {
      y = ph * 15 + r + 4; y = (y < 7) ? 7 : ((y > 479) ? 479 : y);
      x = pw * 15 + c + 4; x = (x < 7) ? 7 : ((x > 479) ? 479 : x);
    }
    int q = y * W + x;
    float rr = img[q], gg = img[HW + q], bb = img[2 * HW + q];
    float nr = rr / A0, ng = gg / A1, nb = bb / A2;
    float mx = fmaxf(fmaxf(nr, ng), nb);
    float mn = fminf(fminf(nr, ng), nb);
    float d = mx + 1e-8f;
    XY[t] = make_float2(1.0f / d, 1.0f - mn / d);   // (V, S) — bit-exact vs old elem1
  }
  __syncthreads();
  float xi = 0.f, yi = 0.f;
  int cnt = 0;
  if (t < PP) {
    xi = XY[t].x; yi = XY[t].y;
    const float4* XY4 = (const float4*)XY;
    int c0 = 0, c1 = 0, c2 = 0, c3 = 0;
    #pragma unroll 2
    for (int j4 = 0; j4 < 112; j4 += 4) {          // covers j = 0..223
      float4 a = XY4[j4 + 0];
      float4 bq = XY4[j4 + 1];
      float4 cq = XY4[j4 + 2];
      float4 dq = XY4[j4 + 3];
      c0 += slptest(xi, yi, a.x, a.y);   c1 += slptest(xi, yi, a.z, a.w);
      c2 += slptest(xi, yi, bq.x, bq.y); c3 += slptest(xi, yi, bq.z, bq.w);
      c0 += slptest(xi, yi, cq.x, cq.y); c1 += slptest(xi, yi, cq.z, cq.w);
      c2 += slptest(xi, yi, dq.x, dq.y); c3 += slptest(xi, yi, dq.z, dq.w);
    }
    { float2 o = XY[224]; c0 += slptest(xi, yi, o.x, o.y); }   // tail j=224
    cnt = (c0 + c1) + (c2 + c3);
  }
  float pmf = (t < PP && cnt >= 113) ? 1.0f : 0.0f;   // scount >= 112.5
  float xm = xi * pmf, ym = yi * pmf;
  float v0 = wred_sum(pmf);
  float v1 = wred_sum(xm);
  float v2 = wred_sum(ym);
  float v3 = wred_sum(xm * ym);
  float v4 = wred_sum(xm * xm);
  float v5 = wred_max((t < PP) ? xm : -INFINITY);
  float v6 = wred_min((t < PP) ? (xi + 1e8f * (1.0f - pmf)) : INFINITY);
  int wid = t >> 6, lane = t & 63;
  if (lane == 0) {
    part[wid][0] = v0; part[wid][1] = v1; part[wid][2] = v2; part[wid][3] = v3;
    part[wid][4] = v4; part[wid][5] = v5; part[wid][6] = v6;
  }
  __syncthreads();
  if (t == 0) {
    float pcount = 0.f, sx = 0.f, sy = 0.f, sxy = 0.f, sxx = 0.f;
    float mxX = -INFINITY, mnX = INFINITY;
    for (int w2 = 0; w2 < 4; ++w2) {
      pcount += part[w2][0]; sx += part[w2][1]; sy += part[w2][2];
      sxy += part[w2][3]; sxx += part[w2][4];
      mxX = fmaxf(mxX, part[w2][5]); mnX = fminf(mnX, part[w2][6]);
    }
    float den = pcount + 1e-5f;
    float mxv = sx / den, myv = sy / den;
    float kk = (sxy - pcount * mxv * myv) / (sxx - pcount * (mxv * mxv) + 1e-5f);
    float bb = myv - kk * mxv;
    float tt = 1.0f + kk / (bb + 1e-8f);
    float len = sqrtf(1.0f + kk * kk) * (mxX - mnX);
    bool m = (pcount > 10.0f) && (len > 0.1f) && (kk > -1.0f) && (kk < 0.0f)
             && (tt > 0.01f) && (tt < 0.99f);
    float res = tt * (m ? 1.0f : 0.0f);   // keep JAX NaN*0 semantics
    if (mode == 0) st->tp1[pid] = res; else st->tp2[pid] = res;
  }
}

// ---------- 6: analytic percentile over t_slp regions (1 block) ----------
__global__ __launch_bounds__(256) void k_pct(State* st) {
  __shared__ unsigned lh[256];
  __shared__ unsigned lds[258];
  __shared__ float tp1s[NPATCH], tp2s[NPATCH];
  int t = threadIdx.x;
  for (int i = t; i < NPATCH; i += 256) { tp1s[i] = st->tp1[i]; tp2s[i] = st->tp2[i]; }
  __syncthreads();
  unsigned prefix = 0u, k = 11521u;   // 1-based rank of sorted[11520]
  for (int level = 0; level < 4; ++level) {
    lh[t] = 0u;
    __syncthreads();
    unsigned mask = (level == 0) ? 0u : (0xFFFFFFFFu << (32 - 8 * level));
    int shift = 24 - 8 * level;
    for (int i = t; i < NPATCH; i += 256) {
      int ph = i >> 5, pw = i & 31;
      float a = tp1s[i];
      int rcnt[2], ridx[2], ccnt[2], cidx[2];
      if (ph == 0) { rcnt[0] = 7; ridx[0] = -1; rcnt[1] = 8; ridx[1] = 0; }
      else         { rcnt[0] = 4; ridx[0] = ph - 1; rcnt[1] = 11; ridx[1] = ph; }
      if (pw == 0) { ccnt[0] = 7; cidx[0] = -1; ccnt[1] = 8; cidx[1] = 0; }
      else         { ccnt[0] = 4; cidx[0] = pw - 1; ccnt[1] = 11; cidx[1] = pw; }
      for (int ri = 0; ri < 2; ++ri)
        for (int ci = 0; ci < 2; ++ci) {
          unsigned area = (unsigned)(rcnt[ri] * ccnt[ci]);
          float bb = 0.0f;
          if (ridx[ri] >= 0 && cidx[ci] >= 0) bb = tp2s[ridx[ri] * 32 + cidx[ci]];
          float r;
          if (a != 0.0f && bb != 0.0f) r = (a + bb) / 2.0f;
          else r = (a != 0.0f) ? a : bb;
          float u = (r > 0.0f) ? r : 10.0f;            // where(t>0,t,10); NaN->10
          unsigned bits = __float_as_uint(u);
          if ((bits & mask) == prefix)
            atomicAdd(&lh[(bits >> shift) & 0xFFu], area);
        }
    }
    __syncthreads();
    unsigned ch, kn;
    resolve_level(lh, k, 0, lds, ch, kn);
    prefix |= ch << shift;
    k = kn;
  }
  if (t == 0) st->tminbits = prefix;
}

// ---------- 7: gf pass-1 horizontal + inline bccr V-maxpool, fused t_fusion, I inline ----------
__global__ __launch_bounds__(512) void k_gf1h(const float* __restrict__ img,
                                              const float* __restrict__ mh,
                                              const State* __restrict__ st,
                                              float4* __restrict__ box4) {
  __shared__ float tp1s[NPATCH], tp2s[NPATCH];
  __shared__ float Pl[540], Il[540];
  __shared__ float tbv[480];
  int y = blockIdx.x, t = threadIdx.x;
  for (int i = t; i < NPATCH; i += 512) { tp1s[i] = st->tp1[i]; tp2s[i] = st->tp2[i]; }
  // inline V-maxpool + clip for row y (bit-exact vs old k_maxV_pct)
  for (int x = t; x < W; x += 512) {
    float m = -INFINITY;
    for (int d = -7; d <= 7; ++d) {
      int yy = y + d;
      float v = ((unsigned)yy < (unsigned)HT) ? mh[yy * W + x] : 0.0f;
      m = fmaxf(m, v);
    }
    tbv[x] = fminf(fmaxf(m, 0.05f), 1.0f);
  }
  __syncthreads();
  float tmin = __uint_as_float(st->tminbits);
  int c1row = (y / 15) * 32;
  bool c2ok = (y >= 7);
  int c2row = c2ok ? ((y - 4) / 15) * 32 : 0;
  for (int i = t; i < 540; i += 512) {
    int col = i - 30;
    float pv = 0.0f, iv = 0.0f;
    if ((unsigned)col < (unsigned)W) {
      int q = y * W + col;
      float a = tp1s[c1row + col / 15];
      float bb = 0.0f;
      if (c2ok && col >= 7) bb = tp2s[c2row + (col - 4) / 15];
      float r;
      if (a != 0.0f && bb != 0.0f) r = (a + bb) / 2.0f;   // NaN != 0 true, as in JAX
      else r = (a != 0.0f) ? a : bb;
      float v = (r > 0.0f) ? r : tbv[col];                // NaN -> tb
      v = (v < tmin) ? tmin : v;
      v = (v > 1.0f) ? 1.0f : v;
      pv = v;
      iv = ((img[q] + img[HW + q]) + img[2 * HW + q]) / 3.0f;  // I inline, bit-exact
    }
    Pl[i] = pv; Il[i] = iv;
  }
  __syncthreads();
  if (t < W) {
    float sI = 0.f, sP = 0.f, sIp = 0.f, sII = 0.f;
    for (int d = 0; d < 61; ++d) {
      float iv = Il[t + d], pv = Pl[t + d];
      sI += iv; sP += pv; sIp += iv * pv; sII += iv * iv;
    }
    box4[y * W + t] = make_float4(sI, sP, sIp, sII);
  }
}

// ---------- 8: gf pass-1 vertical + pass-2 horizontal, fused per-row ----------
__global__ __launch_bounds__(512) void k_gf1vh(const float4* __restrict__ box4,
                                               float2* __restrict__ hab) {
  __shared__ float2 l[540];
  int y = blockIdx.x, t = threadIdx.x;
  float2 v = make_float2(0.f, 0.f);
  if (t < W) {
    float sI = 0.f, sP = 0.f, sIp = 0.f, sII = 0.f;
    for (int d = -30; d <= 30; ++d) {
      int yy = y + d;
      if ((unsigned)yy < (unsigned)HT) {
        float4 b = box4[yy * W + t];
        sI += b.x; sP += b.y; sIp += b.z; sII += b.w;
      }
    }
    int ny = min(y + 30, HT - 1) - max(y - 30, 0) + 1;
    int nx = min(t + 30, W - 1) - max(t - 30, 0) + 1;
    float Nn = (float)(ny * nx);
    float mI = sI / Nn, mP = sP / Nn, mIp = sIp / Nn, mII = sII / Nn;
    float cov = mIp - mI * mP;
    float var = mII - mI * mI;
    float av = cov / (var + 1e-3f);
    v = make_float2(av, mP - av * mI);
  }
  if (t < 30) { l[t] = make_float2(0.f, 0.f); l[510 + t] = make_float2(0.f, 0.f); }
  if (t < W) l[30 + t] = v;
  __syncthreads();
  if (t < W) {
    float sa = 0.f, sb = 0.f;
    for (int d = 0; d < 61; ++d) { float2 u = l[t + d]; sa += u.x; sb += u.y; }
    hab[y * W + t] = make_float2(sa, sb);
  }
}

// ---------- 9: gf pass-2 vertical + restore epilogue (I inline) ----------
__global__ __launch_bounds__(256) void k_gf2vfin(const float2* __restrict__ hab,
                                                 const float* __restrict__ img,
                                                 const State* __restrict__ st,
                                                 float* __restrict__ out) {
  int p = blockIdx.x * 256 + threadIdx.x;
  int y = p / W, x = p - y * W;
  float sa = 0.f, sb = 0.f;
  for (int d = -30; d <= 30; ++d) {
    int yy = y + d;
    if ((unsigned)yy < (unsigned)HT) { float2 v = hab[yy * W + x]; sa += v.x; sb += v.y; }
  }
  int ny = min(y + 30, HT - 1) - max(y - 30, 0) + 1;
  int nx = min(x + 30, W - 1) - max(x - 30, 0) + 1;
  float Nn = (float)(ny * nx);
  float r = img[p], g = img[HW + p], bl = img[2 * HW + p];
  float Iv = ((r + g) + bl) / 3.0f;                       // I inline, bit-exact
  float tref = (sa / Nn) * Iv + (sb / Nn);
  float A0 = st->A[0], A1 = st->A[1], A2 = st->A[2];
  out[p]          = (r  - A0) / tref + A0;
  out[HW + p]     = (g  - A1) / tref + A1;
  out[2 * HW + p] = (bl - A2) / tref + A2;
}

// ---------- launch: 9 dispatches ----------
extern "C" void kernel_launch(void* const* d_in, const int* in_sizes, int n_in,
                              void* d_out, int out_size, void* d_ws, size_t ws_size,
                              hipStream_t stream) {
  (void)in_sizes; (void)n_in; (void)out_size; (void)ws_size;
  const float* img = (const float*)d_in[0];
  float* out = (float*)d_out;
  State* st = (State*)d_ws;
  unsigned* hist16 = (unsigned*)((char*)d_ws + 65536);      // 256 KB
  float* sb = (float*)((char*)d_ws + 65536 + 262144);
  // layout (floats): A=dc [0,HW) ; B=rowmin->mh [HW,2HW) ;
  // box4 [2HW,6HW) ; hab [6HW,8HW)
  float* bufA = sb;
  float* bufB = sb + HW;
  float4* box4 = (float4*)(sb + 2 * HW);
  float2* hab  = (float2*)(sb + 6 * HW);

  dim3 b256(256), b512(512);
  dim3 ge(NT), rows(HT);

  k_rowmin<<<rows, b512, 0, stream>>>(img, bufB, st, hist16);
  k_minV3<<<ge, b256, 0, stream>>>(bufB, bufA, hist16);           // dc + hist16
  k_gather2<<<ge, b256, 0, stream>>>(bufA, img, hist16, st);      // resolve + gather
  k_finalizeA2<<<dim3(1), b256, 0, stream>>>(img, st);
  k_mega1<<<dim3(2048 + HT), b256, 0, stream>>>(img, bufB, st);   // tp1/tp2 + mh
  k_pct<<<dim3(1), b256, 0, stream>>>(st);                        // tminbits
  k_gf1h<<<rows, b512, 0, stream>>>(img, bufB, st, box4);         // inline maxV + box sums
  k_gf1vh<<<rows, b512, 0, stream>>>(box4, hab);
  k_gf2vfin<<<ge, b256, 0, stream>>>(hab, img, st, out);
}

// Round 10
// 176.216 us; speedup vs baseline: 1.1104x; 1.1104x over previous
//
#include <hip/hip_runtime.h>
#include <math.h>

#define W 480
#define HT 480
#define HW (W*HT)
#define NT (HW/256)     // 900 tiles of 256
#define PP 225
#define NPATCH 1024
#define EQCAP 8192

struct State {
  unsigned slotP[4];        // resolved 16-bit bucket + misc
  unsigned slotK[4];        // remaining rank
  float sumA[3];
  unsigned eqCount;
  float A[3];
  unsigned eqIdx[EQCAP];
  unsigned short eqVal[EQCAP];   // low-16 dc bits, written at gather time
  float tp1[NPATCH];
  float tp2[NPATCH];
};

// ---------- radix-select resolve: wave-0 scan, 2 barriers ----------
// Integer-exact match of the original 256-wide Hillis-Steele version:
// exactly one post-mapping position p has cum_excl < k_in <= cum_incl.
// Works for any blockDim >= 64 (scan runs on wave 0 only).
__device__ __forceinline__ void resolve_level(const unsigned* __restrict__ h,
                                              unsigned k_in, int desc,
                                              unsigned* lds,
                                              unsigned& chosen, unsigned& k_out) {
  int t = threadIdx.x;
  if (t < 64) {
    int p0 = 4 * t;
    unsigned c0 = h[desc ? (255 - (p0 + 0)) : (p0 + 0)];
    unsigned c1 = h[desc ? (255 - (p0 + 1)) : (p0 + 1)];
    unsigned c2 = h[desc ? (255 - (p0 + 2)) : (p0 + 2)];
    unsigned c3 = h[desc ? (255 - (p0 + 3)) : (p0 + 3)];
    unsigned s0 = c0, s1 = s0 + c1, s2 = s1 + c2, s3 = s2 + c3;   // lane-local incl
    unsigned incl = s3;
    for (int d = 1; d < 64; d <<= 1) {          // wave inclusive scan, no barriers
      unsigned u = __shfl_up(incl, d, 64);
      if (t >= d) incl += u;
    }
    unsigned lexcl = incl - s3;                  // exclusive prefix of this lane
    unsigned i0 = lexcl + s0, i1 = lexcl + s1, i2 = lexcl + s2, i3 = lexcl + s3;
    unsigned e0 = i0 - c0, e1 = i1 - c1, e2 = i2 - c2, e3 = i3 - c3;
    if (i0 >= k_in && e0 < k_in) { lds[256] = (unsigned)(p0 + 0); lds[257] = k_in - e0; }
    if (i1 >= k_in && e1 < k_in) { lds[256] = (unsigned)(p0 + 1); lds[257] = k_in - e1; }
    if (i2 >= k_in && e2 < k_in) { lds[256] = (unsigned)(p0 + 2); lds[257] = k_in - e2; }
    if (i3 >= k_in && e3 < k_in) { lds[256] = (unsigned)(p0 + 3); lds[257] = k_in - e3; }
  }
  __syncthreads();
  unsigned p = lds[256];
  k_out = lds[257];
  chosen = desc ? (255u - p) : p;
  __syncthreads();          // keep lds[256/257] stable until all have read
}

__device__ __forceinline__ float wred_sum(float v) { for (int m = 32; m; m >>= 1) v += __shfl_xor(v, m, 64); return v; }
__device__ __forceinline__ float wred_max(float v) { for (int m = 32; m; m >>= 1) v = fmaxf(v, __shfl_xor(v, m, 64)); return v; }
__device__ __forceinline__ float wred_min(float v) { for (int m = 32; m; m >>= 1) v = fminf(v, __shfl_xor(v, m, 64)); return v; }

// ---------- 1: init + channel-min + horizontal 55-min (one row per block) ----------
__global__ __launch_bounds__(512) void k_rowmin(const float* __restrict__ img,
                                                float* __restrict__ rowmin,
                                                State* st, unsigned* __restrict__ hist16) {
  __shared__ float l[534];
  int y = blockIdx.x, t = threadIdx.x;
  int g = y * 512 + t;
  if (g < 65536) hist16[g] = 0u;               // zero the 64K-bin histogram
  for (int i = t; i < 534; i += 512) {
    int col = i - 27;
    float v = 1.0f;                              // pad value (constant_values=1.0)
    if ((unsigned)col < (unsigned)W) {
      int q = y * W + col;
      v = fminf(fminf(img[q], img[HW + q]), img[2 * HW + q]);
    }
    l[i] = v;
  }
  if (g == 0) { st->sumA[0] = 0.f; st->sumA[1] = 0.f; st->sumA[2] = 0.f; st->eqCount = 0u; }
  __syncthreads();
  if (t < W) {
    float m = l[t];
    for (int d = 1; d < 55; ++d) m = fminf(m, l[t + d]);
    rowmin[y * W + t] = m;
  }
}

// ---------- 2: vertical 55-min + 16-bit histogram with per-BLOCK dedup (R8 form) ----------
__global__ __launch_bounds__(256) void k_minV3(const float* __restrict__ rowmin,
                                               float* __restrict__ dc,
                                               unsigned* __restrict__ hist16) {
  __shared__ unsigned short bs[256];
  int t = threadIdx.x;
  int p = blockIdx.x * 256 + t;
  int y = p / W, x = p - y * W;
  int lo = y - 27, hi = y + 27;
  float m = (lo < 0 || hi >= HT) ? 1.0f : INFINITY;
  int lo2 = max(lo, 0), hi2 = min(hi, HT - 1);
  for (int yy = lo2; yy <= hi2; ++yy) m = fminf(m, rowmin[yy * W + x]);
  dc[p] = m;
  unsigned b16 = __float_as_uint(m) >> 16;
  bs[t] = (unsigned short)b16;
  __syncthreads();
  // dedup: only the first thread holding each distinct bucket issues the atomic
  int firstIdx = 256, cnt = 0;
  for (int j = 0; j < 256; ++j) {
    if ((unsigned)bs[j] == b16) { ++cnt; if (j < firstIdx) firstIdx = j; }
  }
  if (firstIdx == t) atomicAdd(&hist16[b16], (unsigned)cnt);
}

// ---------- 3: resolve 16-bit bucket of the 230th largest (1 block) ----------
__global__ __launch_bounds__(256) void k_resolve16(const unsigned* __restrict__ hist16,
                                                   State* st) {
  __shared__ unsigned lds[258];
  __shared__ unsigned lh[256];
  int t = threadIdx.x;
  const uint4* h4 = (const uint4*)hist16;
  unsigned s = 0;
  for (int i = 0; i < 64; ++i) { uint4 v = h4[t * 64 + i]; s += v.x + v.y + v.z + v.w; }
  lh[t] = s;
  __syncthreads();
  unsigned ct, kc;
  resolve_level(lh, 230u, 1, lds, ct, kc);      // which 256-bin chunk
  lh[t] = hist16[ct * 256 + t];
  __syncthreads();
  unsigned b, kp;
  resolve_level(lh, kc, 1, lds, b, kp);         // which bin within chunk
  if (t == 0) { st->slotP[0] = (ct << 8) | b; st->slotK[0] = kp; }
}

// ---------- 4: gather strictly-above sums + equal-bucket candidates (LDS-aggregated) ----------
__global__ __launch_bounds__(256) void k_gather2(const float* __restrict__ dc,
                                                 const float* __restrict__ img, State* st) {
  __shared__ float ls[3];
  __shared__ unsigned lcnt, lbase;
  int t = threadIdx.x;
  if (t == 0) { ls[0] = 0.f; ls[1] = 0.f; ls[2] = 0.f; lcnt = 0u; }
  __syncthreads();
  int p = blockIdx.x * 256 + t;
  unsigned p16 = st->slotP[0];
  unsigned bits = __float_as_uint(dc[p]);
  unsigned b16 = bits >> 16;
  bool eq = (b16 == p16);
  unsigned my = 0;
  if (b16 > p16) {
    atomicAdd(&ls[0], img[p]);
    atomicAdd(&ls[1], img[HW + p]);
    atomicAdd(&ls[2], img[2 * HW + p]);
  } else if (eq) {
    my = atomicAdd(&lcnt, 1u);                  // LDS atomic: cheap
  }
  __syncthreads();
  if (t == 0 && lcnt) lbase = atomicAdd(&st->eqCount, lcnt);   // one global atomic/block
  __syncthreads();
  if (eq) {
    unsigned pos = lbase + my;
    if (pos < (unsigned)EQCAP) {
      st->eqIdx[pos] = (unsigned)p;
      st->eqVal[pos] = (unsigned short)(bits & 0xFFFFu);   // save finalize's random gather
    }
  }
  if (t == 0 && (ls[0] != 0.f || ls[1] != 0.f || ls[2] != 0.f)) {
    atomicAdd(&st->sumA[0], ls[0]);
    atomicAdd(&st->sumA[1], ls[1]);
    atomicAdd(&st->sumA[2], ls[2]);
  }
}

// ---------- 5: exact select among equal-bucket: value desc (2 levels), idx asc (3) ----------
__global__ __launch_bounds__(256) void k_finalizeA2(const float* __restrict__ img, State* st) {
  __shared__ unsigned lds[258];
  __shared__ unsigned lh[256];
  __shared__ unsigned sIdx[EQCAP];
  __shared__ unsigned short sVal[EQCAP];
  __shared__ float ssum[3];
  int t = threadIdx.x;
  unsigned k = st->slotK[0];
  unsigned ne = st->eqCount; if (ne > (unsigned)EQCAP) ne = EQCAP;
  for (int i = t; i < (int)ne; i += 256) {       // both streams coalesced
    sIdx[i] = st->eqIdx[i];
    sVal[i] = st->eqVal[i];
  }
  if (t < 3) ssum[t] = 0.f;
  __syncthreads();
  // value select, descending, low-16 bits in 2 byte levels
  unsigned vpfx = 0u;
  for (int lev = 0; lev < 2; ++lev) {
    int s = 8 - 8 * lev;
    lh[t] = 0u;
    __syncthreads();
    for (int i = t; i < (int)ne; i += 256) {
      unsigned v = (unsigned)sVal[i];
      if (lev == 0 || (v >> 8) == (vpfx >> 8))
        atomicAdd(&lh[(v >> s) & 0xFFu], 1u);
    }
    __syncthreads();
    unsigned ch, kn;
    resolve_level(lh, k, 1, lds, ch, kn);
    vpfx |= ch << s;
    k = kn;
  }
  // index select ascending among exact value ties (idx < 2^18: 3 byte levels)
  unsigned pfx = 0u;
  for (int lev = 0; lev < 3; ++lev) {
    int s = 16 - 8 * lev;
    lh[t] = 0u;
    __syncthreads();
    for (int i = t; i < (int)ne; i += 256) {
      if ((unsigned)sVal[i] == vpfx) {
        unsigned v = sIdx[i];
        if ((v >> (s + 8)) == (pfx >> (s + 8)))
          atomicAdd(&lh[(v >> s) & 0xFFu], 1u);
      }
    }
    __syncthreads();
    unsigned ch, kn;
    resolve_level(lh, k, 0, lds, ch, kn);
    pfx |= ch << s;
    k = kn;
  }
  // selected: value > vpfx, or value == vpfx and idx <= pfx
  float a0 = 0.f, a1 = 0.f, a2 = 0.f;
  for (int i = t; i < (int)ne; i += 256) {
    unsigned v = (unsigned)sVal[i], q = sIdx[i];
    if (v > vpfx || (v == vpfx && q <= pfx)) {
      a0 += img[q]; a1 += img[HW + q]; a2 += img[2 * HW + q];
    }
  }
  atomicAdd(&ssum[0], a0); atomicAdd(&ssum[1], a1); atomicAdd(&ssum[2], a2);
  __syncthreads();
  if (t == 0) {
    st->A[0] = (st->sumA[0] + ssum[0]) / 230.0f;
    st->A[1] = (st->sumA[1] + ssum[1]) / 230.0f;
    st->A[2] = (st->sumA[2] + ssum[2]) / 230.0f;
  }
}

// pair test: slope in (-1,0)  <=>  dY*D < 0  AND  |dY| < |D|
// fp32-boolean-identical single-expression form: dY*(dY+D) < 0 (verified R7/R8)
__device__ __forceinline__ int slptest(float xi, float yi, float ox, float oy) {
  float dY = yi - oy;
  float D = (xi - ox) + 1e-8f;
  return (dY * (dY + D) < 0.0f) ? 1 : 0;
}

// ---------- 6: patch grids (SV inline) + bccr To+H-maxpool per row ----------
__global__ __launch_bounds__(256) void k_mega1(const float* __restrict__ img,
                                               float* __restrict__ mh, State* st) {
  __shared__ __align__(16) float2 XY[PP + 1];
  __shared__ float part[4][8];
  __shared__ float Tl[494];
  int b = blockIdx.x;
  int t = threadIdx.x;
  float A0 = st->A[0], A1 = st->A[1], A2 = st->A[2];
  const float c20 = (float)(20.0 / 255.0);
  const float c300 = (float)(300.0 / 255.0);
  if (b >= 2048) {   // bccr: compute To inline for one row, 15-tap horizontal max (pad 0)
    int y = b - 2048;
    for (int i = t; i < 494; i += 256) {
      int col = i - 7;
      float v = 0.0f;
      if ((unsigned)col < (unsigned)W) {
        int q = y * W + col;
        float r = img[q], g = img[HW + q], bl = img[2 * HW + q];
        float t0 = fmaxf((A0 - r) / (A0 - c20), (A0 - r) / (A0 - c300));
        float t1 = fmaxf((A1 - g) / (A1 - c20), (A1 - g) / (A1 - c300));
        float t2 = fmaxf((A2 - bl) / (A2 - c20), (A2 - bl) / (A2 - c300));
        v = fmaxf(fmaxf(t0, t1), t2);
      }
      Tl[i] = v;
    }
    __syncthreads();
    for (int x = t; x < W; x += 256) {
      float m = -INFINITY;
      for (int d = 0; d < 15; ++d) m = fmaxf(m, Tl[x + d]);
      mh[y * W + x] = m;
    }
    return;
  }
  int mode = b >> 10;              // 0: t1 grid, 1: shifted t2 grid
  int pid = b & 1023;
  int ph = pid >> 5, pw = pid & 31;
  if (t < PP) {
    int r = t / 15, c = t - (t / 15) * 15;
    int y, x;
    if (mode == 0) { y = ph * 15 + r; x = pw * 15 + c; }
    else {
      y = ph * 15 + r + 4; y = (y < 7) ? 7 : ((y > 479) ? 479 : y);
      x = pw * 15 + c + 4; x = (x < 7) ? 7 : ((x > 479) ? 479 : x);
    }
    int q = y * W + x;
    float rr = img[q], gg = img[HW + q], bb = img[2 * HW + q];
    float nr = rr / A0, ng = gg / A1, nb = bb / A2;
    float mx = fmaxf(fmaxf(nr, ng), nb);
    float mn = fminf(fminf(nr, ng), nb);
    float d = mx + 1e-8f;
    XY[t] = make_float2(1.0f / d, 1.0f - mn / d);   // (V, S) — bit-exact vs old elem1
  }
  __syncthreads();
  float xi = 0.f, yi = 0.f;
  int cnt = 0;
  if (t < PP) {
    xi = XY[t].x; yi = XY[t].y;
    const float4* XY4 = (const float4*)XY;
    int c0 = 0, c1 = 0, c2 = 0, c3 = 0;
    #pragma unroll 2
    for (int j4 = 0; j4 < 112; j4 += 4) {          // covers j = 0..223
      float4 a = XY4[j4 + 0];
      float4 bq = XY4[j4 + 1];
      float4 cq = XY4[j4 + 2];
      float4 dq = XY4[j4 + 3];
      c0 += slptest(xi, yi, a.x, a.y);   c1 += slptest(xi, yi, a.z, a.w);
      c2 += slptest(xi, yi, bq.x, bq.y); c3 += slptest(xi, yi, bq.z, bq.w);
      c0 += slptest(xi, yi, cq.x, cq.y); c1 += slptest(xi, yi, cq.z, cq.w);
      c2 += slptest(xi, yi, dq.x, dq.y); c3 += slptest(xi, yi, dq.z, dq.w);
    }
    { float2 o = XY[224]; c0 += slptest(xi, yi, o.x, o.y); }   // tail j=224
    cnt = (c0 + c1) + (c2 + c3);
  }
  float pmf = (t < PP && cnt >= 113) ? 1.0f : 0.0f;   // scount >= 112.5
  float xm = xi * pmf, ym = yi * pmf;
  float v0 = wred_sum(pmf);
  float v1 = wred_sum(xm);
  float v2 = wred_sum(ym);
  float v3 = wred_sum(xm * ym);
  float v4 = wred_sum(xm * xm);
  float v5 = wred_max((t < PP) ? xm : -INFINITY);
  float v6 = wred_min((t < PP) ? (xi + 1e8f * (1.0f - pmf)) : INFINITY);
  int wid = t >> 6, lane = t & 63;
  if (lane == 0) {
    part[wid][0] = v0; part[wid][1] = v1; part[wid][2] = v2; part[wid][3] = v3;
    part[wid][4] = v4; part[wid][5] = v5; part[wid][6] = v6;
  }
  __syncthreads();
  if (t == 0) {
    float pcount = 0.f, sx = 0.f, sy = 0.f, sxy = 0.f, sxx = 0.f;
    float mxX = -INFINITY, mnX = INFINITY;
    for (int w2 = 0; w2 < 4; ++w2) {
      pcount += part[w2][0]; sx += part[w2][1]; sy += part[w2][2];
      sxy += part[w2][3]; sxx += part[w2][4];
      mxX = fmaxf(mxX, part[w2][5]); mnX = fminf(mnX, part[w2][6]);
    }
    float den = pcount + 1e-5f;
    float mxv = sx / den, myv = sy / den;
    float kk = (sxy - pcount * mxv * myv) / (sxx - pcount * (mxv * mxv) + 1e-5f);
    float bb = myv - kk * mxv;
    float tt = 1.0f + kk / (bb + 1e-8f);
    float len = sqrtf(1.0f + kk * kk) * (mxX - mnX);
    bool m = (pcount > 10.0f) && (len > 0.1f) && (kk > -1.0f) && (kk < 0.0f)
             && (tt > 0.01f) && (tt < 0.99f);
    float res = tt * (m ? 1.0f : 0.0f);   // keep JAX NaN*0 semantics
    if (mode == 0) st->tp1[pid] = res; else st->tp2[pid] = res;
  }
}

// ---------- 7: gf pass-1 horizontal + inline V-maxpool + REPLICATED percentile ----------
// The percentile replica reads only tp1/tp2 (8 KB, already loaded into LDS for
// t_fusion) — every block deterministically computes the identical tminbits.
__global__ __launch_bounds__(512) void k_gf1h(const float* __restrict__ img,
                                              const float* __restrict__ mh,
                                              const State* __restrict__ st,
                                              float4* __restrict__ box4) {
  __shared__ float tp1s[NPATCH], tp2s[NPATCH];
  __shared__ float Pl[540], Il[540];
  __shared__ float tbv[480];
  __shared__ unsigned lh[256];
  __shared__ unsigned lds[258];
  int y = blockIdx.x, t = threadIdx.x;
  for (int i = t; i < NPATCH; i += 512) { tp1s[i] = st->tp1[i]; tp2s[i] = st->tp2[i]; }
  // inline V-maxpool + clip for row y (bit-exact vs old k_maxV_pct)
  for (int x = t; x < W; x += 512) {
    float m = -INFINITY;
    for (int d = -7; d <= 7; ++d) {
      int yy = y + d;
      float v = ((unsigned)yy < (unsigned)HT) ? mh[yy * W + x] : 0.0f;
      m = fmaxf(m, v);
    }
    tbv[x] = fminf(fmaxf(m, 0.05f), 1.0f);
  }
  __syncthreads();
  // ---- replicated percentile (was k_pct): 4-level radix select on region areas ----
  unsigned prefix = 0u, k = 11521u;   // 1-based rank of sorted[11520]
  for (int level = 0; level < 4; ++level) {
    if (t < 256) lh[t] = 0u;
    __syncthreads();
    unsigned mask = (level == 0) ? 0u : (0xFFFFFFFFu << (32 - 8 * level));
    int shift = 24 - 8 * level;
    for (int i = t; i < NPATCH; i += 512) {
      int ph = i >> 5, pw = i & 31;
      float a = tp1s[i];
      int rcnt[2], ridx[2], ccnt[2], cidx[2];
      if (ph == 0) { rcnt[0] = 7; ridx[0] = -1; rcnt[1] = 8; ridx[1] = 0; }
      else         { rcnt[0] = 4; ridx[0] = ph - 1; rcnt[1] = 11; ridx[1] = ph; }
      if (pw == 0) { ccnt[0] = 7; cidx[0] = -1; ccnt[1] = 8; cidx[1] = 0; }
      else         { ccnt[0] = 4; cidx[0] = pw - 1; ccnt[1] = 11; cidx[1] = pw; }
      for (int ri = 0; ri < 2; ++ri)
        for (int ci = 0; ci < 2; ++ci) {
          unsigned area = (unsigned)(rcnt[ri] * ccnt[ci]);
          float bb = 0.0f;
          if (ridx[ri] >= 0 && cidx[ci] >= 0) bb = tp2s[ridx[ri] * 32 + cidx[ci]];
          float r;
          if (a != 0.0f && bb != 0.0f) r = (a + bb) / 2.0f;
          else r = (a != 0.0f) ? a : bb;
          float u = (r > 0.0f) ? r : 10.0f;            // where(t>0,t,10); NaN->10
          unsigned bits = __float_as_uint(u);
          if ((bits & mask) == prefix)
            atomicAdd(&lh[(bits >> shift) & 0xFFu], area);
        }
    }
    __syncthreads();
    unsigned ch, kn;
    resolve_level(lh, k, 0, lds, ch, kn);
    prefix |= ch << shift;
    k = kn;
  }
  float tmin = __uint_as_float(prefix);
  // ---- t_fusion + I + horizontal 61-box sums ----
  int c1row = (y / 15) * 32;
  bool c2ok = (y >= 7);
  int c2row = c2ok ? ((y - 4) / 15) * 32 : 0;
  for (int i = t; i < 540; i += 512) {
    int col = i - 30;
    float pv = 0.0f, iv = 0.0f;
    if ((unsigned)col < (unsigned)W) {
      int q = y * W + col;
      float a = tp1s[c1row + col / 15];
      float bb = 0.0f;
      if (c2ok && col >= 7) bb = tp2s[c2row + (col - 4) / 15];
      float r;
      if (a != 0.0f && bb != 0.0f) r = (a + bb) / 2.0f;   // NaN != 0 true, as in JAX
      else r = (a != 0.0f) ? a : bb;
      float v = (r > 0.0f) ? r : tbv[col];                // NaN -> tb
      v = (v < tmin) ? tmin : v;
      v = (v > 1.0f) ? 1.0f : v;
      pv = v;
      iv = ((img[q] + img[HW + q]) + img[2 * HW + q]) / 3.0f;  // I inline, bit-exact
    }
    Pl[i] = pv; Il[i] = iv;
  }
  __syncthreads();
  if (t < W) {
    float sI = 0.f, sP = 0.f, sIp = 0.f, sII = 0.f;
    for (int d = 0; d < 61; ++d) {
      float iv = Il[t + d], pv = Pl[t + d];
      sI += iv; sP += pv; sIp += iv * pv; sII += iv * iv;
    }
    box4[y * W + t] = make_float4(sI, sP, sIp, sII);
  }
}

// ---------- 8: gf pass-1 vertical + pass-2 horizontal, fused per-row ----------
__global__ __launch_bounds__(512) void k_gf1vh(const float4* __restrict__ box4,
                                               float2* __restrict__ hab) {
  __shared__ float2 l[540];
  int y = blockIdx.x, t = threadIdx.x;
  float2 v = make_float2(0.f, 0.f);
  if (t < W) {
    float sI = 0.f, sP = 0.f, sIp = 0.f, sII = 0.f;
    for (int d = -30; d <= 30; ++d) {
      int yy = y + d;
      if ((unsigned)yy < (unsigned)HT) {
        float4 b = box4[yy * W + t];
        sI += b.x; sP += b.y; sIp += b.z; sII += b.w;
      }
    }
    int ny = min(y + 30, HT - 1) - max(y - 30, 0) + 1;
    int nx = min(t + 30, W - 1) - max(t - 30, 0) + 1;
    float Nn = (float)(ny * nx);
    float mI = sI / Nn, mP = sP / Nn, mIp = sIp / Nn, mII = sII / Nn;
    float cov = mIp - mI * mP;
    float var = mII - mI * mI;
    float av = cov / (var + 1e-3f);
    v = make_float2(av, mP - av * mI);
  }
  if (t < 30) { l[t] = make_float2(0.f, 0.f); l[510 + t] = make_float2(0.f, 0.f); }
  if (t < W) l[30 + t] = v;
  __syncthreads();
  if (t < W) {
    float sa = 0.f, sb = 0.f;
    for (int d = 0; d < 61; ++d) { float2 u = l[t + d]; sa += u.x; sb += u.y; }
    hab[y * W + t] = make_float2(sa, sb);
  }
}

// ---------- 9: gf pass-2 vertical + restore epilogue (I inline) ----------
__global__ __launch_bounds__(256) void k_gf2vfin(const float2* __restrict__ hab,
                                                 const float* __restrict__ img,
                                                 const State* __restrict__ st,
                                                 float* __restrict__ out) {
  int p = blockIdx.x * 256 + threadIdx.x;
  int y = p / W, x = p - y * W;
  float sa = 0.f, sb = 0.f;
  for (int d = -30; d <= 30; ++d) {
    int yy = y + d;
    if ((unsigned)yy < (unsigned)HT) { float2 v = hab[yy * W + x]; sa += v.x; sb += v.y; }
  }
  int ny = min(y + 30, HT - 1) - max(y - 30, 0) + 1;
  int nx = min(x + 30, W - 1) - max(x - 30, 0) + 1;
  float Nn = (float)(ny * nx);
  float r = img[p], g = img[HW + p], bl = img[2 * HW + p];
  float Iv = ((r + g) + bl) / 3.0f;                       // I inline, bit-exact
  float tref = (sa / Nn) * Iv + (sb / Nn);
  float A0 = st->A[0], A1 = st->A[1], A2 = st->A[2];
  out[p]          = (r  - A0) / tref + A0;
  out[HW + p]     = (g  - A1) / tref + A1;
  out[2 * HW + p] = (bl - A2) / tref + A2;
}

// ---------- launch: 9 dispatches ----------
extern "C" void kernel_launch(void* const* d_in, const int* in_sizes, int n_in,
                              void* d_out, int out_size, void* d_ws, size_t ws_size,
                              hipStream_t stream) {
  (void)in_sizes; (void)n_in; (void)out_size; (void)ws_size;
  const float* img = (const float*)d_in[0];
  float* out = (float*)d_out;
  State* st = (State*)d_ws;
  unsigned* hist16 = (unsigned*)((char*)d_ws + 65536);      // 256 KB
  float* sb = (float*)((char*)d_ws + 65536 + 262144);
  // layout (floats): A=dc [0,HW) ; B=rowmin->mh [HW,2HW) ;
  // box4 [2HW,6HW) ; hab [6HW,8HW)
  float* bufA = sb;
  float* bufB = sb + HW;
  float4* box4 = (float4*)(sb + 2 * HW);
  float2* hab  = (float2*)(sb + 6 * HW);

  dim3 b256(256), b512(512);
  dim3 ge(NT), rows(HT);

  k_rowmin<<<rows, b512, 0, stream>>>(img, bufB, st, hist16);
  k_minV3<<<ge, b256, 0, stream>>>(bufB, bufA, hist16);           // dc + hist16
  k_resolve16<<<dim3(1), b256, 0, stream>>>(hist16, st);
  k_gather2<<<ge, b256, 0, stream>>>(bufA, img, st);
  k_finalizeA2<<<dim3(1), b256, 0, stream>>>(img, st);
  k_mega1<<<dim3(2048 + HT), b256, 0, stream>>>(img, bufB, st);   // tp1/tp2 + mh
  k_gf1h<<<rows, b512, 0, stream>>>(img, bufB, st, box4);         // maxV + pct + box sums
  k_gf1vh<<<rows, b512, 0, stream>>>(box4, hab);
  k_gf2vfin<<<ge, b256, 0, stream>>>(hab, img, st, out);
}

// Round 12
// 175.387 us; speedup vs baseline: 1.1156x; 1.0047x over previous
//
#include <hip/hip_runtime.h>
#include <math.h>

#define W 480
#define HT 480
#define HW (W*HT)
#define NT (HW/256)     // 900 tiles of 256
#define PP 225
#define NPATCH 1024
#define EQCAP 8192

struct State {
  unsigned slotP[4];        // resolved 16-bit bucket + misc
  unsigned slotK[4];        // remaining rank
  float sumA[3];
  unsigned eqCount;
  float A[3];
  unsigned eqIdx[EQCAP];
  unsigned short eqVal[EQCAP];   // low-16 dc bits, written at gather time
  float tp1[NPATCH];
  float tp2[NPATCH];
};

// ---------- radix-select resolve: wave-0 scan, 2 barriers ----------
// Integer-exact match of the original 256-wide Hillis-Steele version:
// exactly one post-mapping position p has cum_excl < k_in <= cum_incl.
// Works for any blockDim >= 64 (scan runs on wave 0 only).
__device__ __forceinline__ void resolve_level(const unsigned* __restrict__ h,
                                              unsigned k_in, int desc,
                                              unsigned* lds,
                                              unsigned& chosen, unsigned& k_out) {
  int t = threadIdx.x;
  if (t < 64) {
    int p0 = 4 * t;
    unsigned c0 = h[desc ? (255 - (p0 + 0)) : (p0 + 0)];
    unsigned c1 = h[desc ? (255 - (p0 + 1)) : (p0 + 1)];
    unsigned c2 = h[desc ? (255 - (p0 + 2)) : (p0 + 2)];
    unsigned c3 = h[desc ? (255 - (p0 + 3)) : (p0 + 3)];
    unsigned s0 = c0, s1 = s0 + c1, s2 = s1 + c2, s3 = s2 + c3;   // lane-local incl
    unsigned incl = s3;
    for (int d = 1; d < 64; d <<= 1) {          // wave inclusive scan, no barriers
      unsigned u = __shfl_up(incl, d, 64);
      if (t >= d) incl += u;
    }
    unsigned lexcl = incl - s3;                  // exclusive prefix of this lane
    unsigned i0 = lexcl + s0, i1 = lexcl + s1, i2 = lexcl + s2, i3 = lexcl + s3;
    unsigned e0 = i0 - c0, e1 = i1 - c1, e2 = i2 - c2, e3 = i3 - c3;
    if (i0 >= k_in && e0 < k_in) { lds[256] = (unsigned)(p0 + 0); lds[257] = k_in - e0; }
    if (i1 >= k_in && e1 < k_in) { lds[256] = (unsigned)(p0 + 1); lds[257] = k_in - e1; }
    if (i2 >= k_in && e2 < k_in) { lds[256] = (unsigned)(p0 + 2); lds[257] = k_in - e2; }
    if (i3 >= k_in && e3 < k_in) { lds[256] = (unsigned)(p0 + 3); lds[257] = k_in - e3; }
  }
  __syncthreads();
  unsigned p = lds[256];
  k_out = lds[257];
  chosen = desc ? (255u - p) : p;
  __syncthreads();          // keep lds[256/257] stable until all have read
}

__device__ __forceinline__ float wred_sum(float v) { for (int m = 32; m; m >>= 1) v += __shfl_xor(v, m, 64); return v; }
__device__ __forceinline__ float wred_max(float v) { for (int m = 32; m; m >>= 1) v = fmaxf(v, __shfl_xor(v, m, 64)); return v; }
__device__ __forceinline__ float wred_min(float v) { for (int m = 32; m; m >>= 1) v = fminf(v, __shfl_xor(v, m, 64)); return v; }

// ---------- 1: init + channel-min + horizontal 55-min (one row per block) ----------
__global__ __launch_bounds__(512) void k_rowmin(const float* __restrict__ img,
                                                float* __restrict__ rowmin,
                                                State* st, unsigned* __restrict__ hist16) {
  __shared__ float l[534];
  int y = blockIdx.x, t = threadIdx.x;
  int g = y * 512 + t;
  if (g < 65536) hist16[g] = 0u;               // zero the 64K-bin histogram
  for (int i = t; i < 534; i += 512) {
    int col = i - 27;
    float v = 1.0f;                              // pad value (constant_values=1.0)
    if ((unsigned)col < (unsigned)W) {
      int q = y * W + col;
      v = fminf(fminf(img[q], img[HW + q]), img[2 * HW + q]);
    }
    l[i] = v;
  }
  if (g == 0) { st->sumA[0] = 0.f; st->sumA[1] = 0.f; st->sumA[2] = 0.f; st->eqCount = 0u; }
  __syncthreads();
  if (t < W) {
    float m = l[t];
    for (int d = 1; d < 55; ++d) m = fminf(m, l[t + d]);
    rowmin[y * W + t] = m;
  }
}

// ---------- 2: vertical 55-min + 16-bit histogram with per-BLOCK dedup (R8 form) ----------
__global__ __launch_bounds__(256) void k_minV3(const float* __restrict__ rowmin,
                                               float* __restrict__ dc,
                                               unsigned* __restrict__ hist16) {
  __shared__ unsigned short bs[256];
  int t = threadIdx.x;
  int p = blockIdx.x * 256 + t;
  int y = p / W, x = p - y * W;
  int lo = y - 27, hi = y + 27;
  float m = (lo < 0 || hi >= HT) ? 1.0f : INFINITY;
  int lo2 = max(lo, 0), hi2 = min(hi, HT - 1);
  for (int yy = lo2; yy <= hi2; ++yy) m = fminf(m, rowmin[yy * W + x]);
  dc[p] = m;
  unsigned b16 = __float_as_uint(m) >> 16;
  bs[t] = (unsigned short)b16;
  __syncthreads();
  // dedup: only the first thread holding each distinct bucket issues the atomic
  int firstIdx = 256, cnt = 0;
  for (int j = 0; j < 256; ++j) {
    if ((unsigned)bs[j] == b16) { ++cnt; if (j < firstIdx) firstIdx = j; }
  }
  if (firstIdx == t) atomicAdd(&hist16[b16], (unsigned)cnt);
}

// ---------- 3: resolve 16-bit bucket of the 230th largest (1 block) ----------
__global__ __launch_bounds__(256) void k_resolve16(const unsigned* __restrict__ hist16,
                                                   State* st) {
  __shared__ unsigned lds[258];
  __shared__ unsigned lh[256];
  int t = threadIdx.x;
  const uint4* h4 = (const uint4*)hist16;
  unsigned s = 0;
  for (int i = 0; i < 64; ++i) { uint4 v = h4[t * 64 + i]; s += v.x + v.y + v.z + v.w; }
  lh[t] = s;
  __syncthreads();
  unsigned ct, kc;
  resolve_level(lh, 230u, 1, lds, ct, kc);      // which 256-bin chunk
  lh[t] = hist16[ct * 256 + t];
  __syncthreads();
  unsigned b, kp;
  resolve_level(lh, kc, 1, lds, b, kp);         // which bin within chunk
  if (t == 0) { st->slotP[0] = (ct << 8) | b; st->slotK[0] = kp; }
}

// ---------- 4: gather strictly-above sums + equal-bucket candidates (LDS-aggregated) ----------
__global__ __launch_bounds__(256) void k_gather2(const float* __restrict__ dc,
                                                 const float* __restrict__ img, State* st) {
  __shared__ float ls[3];
  __shared__ unsigned lcnt, lbase;
  int t = threadIdx.x;
  if (t == 0) { ls[0] = 0.f; ls[1] = 0.f; ls[2] = 0.f; lcnt = 0u; }
  __syncthreads();
  int p = blockIdx.x * 256 + t;
  unsigned p16 = st->slotP[0];
  unsigned bits = __float_as_uint(dc[p]);
  unsigned b16 = bits >> 16;
  bool eq = (b16 == p16);
  unsigned my = 0;
  if (b16 > p16) {
    atomicAdd(&ls[0], img[p]);
    atomicAdd(&ls[1], img[HW + p]);
    atomicAdd(&ls[2], img[2 * HW + p]);
  } else if (eq) {
    my = atomicAdd(&lcnt, 1u);                  // LDS atomic: cheap
  }
  __syncthreads();
  if (t == 0 && lcnt) lbase = atomicAdd(&st->eqCount, lcnt);   // one global atomic/block
  __syncthreads();
  if (eq) {
    unsigned pos = lbase + my;
    if (pos < (unsigned)EQCAP) {
      st->eqIdx[pos] = (unsigned)p;
      st->eqVal[pos] = (unsigned short)(bits & 0xFFFFu);   // save finalize's random gather
    }
  }
  if (t == 0 && (ls[0] != 0.f || ls[1] != 0.f || ls[2] != 0.f)) {
    atomicAdd(&st->sumA[0], ls[0]);
    atomicAdd(&st->sumA[1], ls[1]);
    atomicAdd(&st->sumA[2], ls[2]);
  }
}

// ---------- 5: exact select among equal-bucket: value desc (2 levels), idx asc (3) ----------
__global__ __launch_bounds__(256) void k_finalizeA2(const float* __restrict__ img, State* st) {
  __shared__ unsigned lds[258];
  __shared__ unsigned lh[256];
  __shared__ unsigned sIdx[EQCAP];
  __shared__ unsigned short sVal[EQCAP];
  __shared__ float ssum[3];
  int t = threadIdx.x;
  unsigned k = st->slotK[0];
  unsigned ne = st->eqCount; if (ne > (unsigned)EQCAP) ne = EQCAP;
  for (int i = t; i < (int)ne; i += 256) {       // both streams coalesced
    sIdx[i] = st->eqIdx[i];
    sVal[i] = st->eqVal[i];
  }
  if (t < 3) ssum[t] = 0.f;
  __syncthreads();
  // value select, descending, low-16 bits in 2 byte levels
  unsigned vpfx = 0u;
  for (int lev = 0; lev < 2; ++lev) {
    int s = 8 - 8 * lev;
    lh[t] = 0u;
    __syncthreads();
    for (int i = t; i < (int)ne; i += 256) {
      unsigned v = (unsigned)sVal[i];
      if (lev == 0 || (v >> 8) == (vpfx >> 8))
        atomicAdd(&lh[(v >> s) & 0xFFu], 1u);
    }
    __syncthreads();
    unsigned ch, kn;
    resolve_level(lh, k, 1, lds, ch, kn);
    vpfx |= ch << s;
    k = kn;
  }
  // index select ascending among exact value ties (idx < 2^18: 3 byte levels)
  unsigned pfx = 0u;
  for (int lev = 0; lev < 3; ++lev) {
    int s = 16 - 8 * lev;
    lh[t] = 0u;
    __syncthreads();
    for (int i = t; i < (int)ne; i += 256) {
      if ((unsigned)sVal[i] == vpfx) {
        unsigned v = sIdx[i];
        if ((v >> (s + 8)) == (pfx >> (s + 8)))
          atomicAdd(&lh[(v >> s) & 0xFFu], 1u);
      }
    }
    __syncthreads();
    unsigned ch, kn;
    resolve_level(lh, k, 0, lds, ch, kn);
    pfx |= ch << s;
    k = kn;
  }
  // selected: value > vpfx, or value == vpfx and idx <= pfx
  float a0 = 0.f, a1 = 0.f, a2 = 0.f;
  for (int i = t; i < (int)ne; i += 256) {
    unsigned v = (unsigned)sVal[i], q = sIdx[i];
    if (v > vpfx || (v == vpfx && q <= pfx)) {
      a0 += img[q]; a1 += img[HW + q]; a2 += img[2 * HW + q];
    }
  }
  atomicAdd(&ssum[0], a0); atomicAdd(&ssum[1], a1); atomicAdd(&ssum[2], a2);
  __syncthreads();
  if (t == 0) {
    st->A[0] = (st->sumA[0] + ssum[0]) / 230.0f;
    st->A[1] = (st->sumA[1] + ssum[1]) / 230.0f;
    st->A[2] = (st->sumA[2] + ssum[2]) / 230.0f;
  }
}

// pair test: slope in (-1,0)  <=>  dY*D < 0  AND  |dY| < |D|
// fp32-boolean-identical single-expression form: dY*(dY+D) < 0 (verified R7/R8)
__device__ __forceinline__ int slptest(float xi, float yi, float ox, float oy) {
  float dY = yi - oy;
  float D = (xi - ox) + 1e-8f;
  return (dY * (dY + D) < 0.0f) ? 1 : 0;
}

// ---------- 6: patch grids (SV inline) + bccr To+H-maxpool per row ----------
__global__ __launch_bounds__(256) void k_mega1(const float* __restrict__ img,
                                               float* __restrict__ mh, State* st) {
  __shared__ __align__(16) float2 XY[PP + 1];
  __shared__ float part[4][8];
  __shared__ float Tl[494];
  int b = blockIdx.x;
  int t = threadIdx.x;
  float A0 = st->A[0], A1 = st->A[1], A2 = st->A[2];
  const float c20 = (float)(20.0 / 255.0);
  const float c300 = (float)(300.0 / 255.0);
  if (b >= 2048) {   // bccr: compute To inline for one row, 15-tap horizontal max (pad 0)
    int y = b - 2048;
    for (int i = t; i < 494; i += 256) {
      int col = i - 7;
      float v = 0.0f;
      if ((unsigned)col < (unsigned)W) {
        int q = y * W + col;
        float r = img[q], g = img[HW + q], bl = img[2 * HW + q];
        float t0 = fmaxf((A0 - r) / (A0 - c20), (A0 - r) / (A0 - c300));
        float t1 = fmaxf((A1 - g) / (A1 - c20), (A1 - g) / (A1 - c300));
        float t2 = fmaxf((A2 - bl) / (A2 - c20), (A2 - bl) / (A2 - c300));
        v = fmaxf(fmaxf(t0, t1), t2);
      }
      Tl[i] = v;
    }
    __syncthreads();
    for (int x = t; x < W; x += 256) {
      float m = -INFINITY;
      for (int d = 0; d < 15; ++d) m = fmaxf(m, Tl[x + d]);
      mh[y * W + x] = m;
    }
    return;
  }
  int mode = b >> 10;              // 0: t1 grid, 1: shifted t2 grid
  int pid = b & 1023;
  int ph = pid >> 5, pw = pid & 31;
  if (t < PP) {
    int r = t / 15, c = t - (t / 15) * 15;
    int y, x;
    if (mode == 0) { y = ph * 15 + r; x = pw * 15 + c; }
    else {
      y = ph * 15 + r + 4; y = (y < 7) ? 7 : ((y > 479) ? 479 : y);
      x = pw * 15 + c + 4; x = (x < 7) ? 7 : ((x > 479) ? 479 : x);
    }
    int q = y * W + x;
    float rr = img[q], gg = img[HW + q], bb = img[2 * HW + q];
    float nr = rr / A0, ng = gg / A1, nb = bb / A2;
    float mx = fmaxf(fmaxf(nr, ng), nb);
    float mn = fminf(fminf(nr, ng), nb);
    float d = mx + 1e-8f;
    XY[t] = make_float2(1.0f / d, 1.0f - mn / d);   // (V, S) — bit-exact vs old elem1
  }
  __syncthreads();
  float xi = 0.f, yi = 0.f;
  int cnt = 0;
  if (t < PP) {
    xi = XY[t].x; yi = XY[t].y;
    const float4* XY4 = (const float4*)XY;
    int c0 = 0, c1 = 0, c2 = 0, c3 = 0;
    #pragma unroll 2
    for (int j4 = 0; j4 < 112; j4 += 4) {          // covers j = 0..223
      float4 a = XY4[j4 + 0];
      float4 bq = XY4[j4 + 1];
      float4 cq = XY4[j4 + 2];
      float4 dq = XY4[j4 + 3];
      c0 += slptest(xi, yi, a.x, a.y);   c1 += slptest(xi, yi, a.z, a.w);
      c2 += slptest(xi, yi, bq.x, bq.y); c3 += slptest(xi, yi, bq.z, bq.w);
      c0 += slptest(xi, yi, cq.x, cq.y); c1 += slptest(xi, yi, cq.z, cq.w);
      c2 += slptest(xi, yi, dq.x, dq.y); c3 += slptest(xi, yi, dq.z, dq.w);
    }
    { float2 o = XY[224]; c0 += slptest(xi, yi, o.x, o.y); }   // tail j=224
    cnt = (c0 + c1) + (c2 + c3);
  }
  float pmf = (t < PP && cnt >= 113) ? 1.0f : 0.0f;   // scount >= 112.5
  float xm = xi * pmf, ym = yi * pmf;
  float v0 = wred_sum(pmf);
  float v1 = wred_sum(xm);
  float v2 = wred_sum(ym);
  float v3 = wred_sum(xm * ym);
  float v4 = wred_sum(xm * xm);
  float v5 = wred_max((t < PP) ? xm : -INFINITY);
  float v6 = wred_min((t < PP) ? (xi + 1e8f * (1.0f - pmf)) : INFINITY);
  int wid = t >> 6, lane = t & 63;
  if (lane == 0) {
    part[wid][0] = v0; part[wid][1] = v1; part[wid][2] = v2; part[wid][3] = v3;
    part[wid][4] = v4; part[wid][5] = v5; part[wid][6] = v6;
  }
  __syncthreads();
  if (t == 0) {
    float pcount = 0.f, sx = 0.f, sy = 0.f, sxy = 0.f, sxx = 0.f;
    float mxX = -INFINITY, mnX = INFINITY;
    for (int w2 = 0; w2 < 4; ++w2) {
      pcount += part[w2][0]; sx += part[w2][1]; sy += part[w2][2];
      sxy += part[w2][3]; sxx += part[w2][4];
      mxX = fmaxf(mxX, part[w2][5]); mnX = fminf(mnX, part[w2][6]);
    }
    float den = pcount + 1e-5f;
    float mxv = sx / den, myv = sy / den;
    float kk = (sxy - pcount * mxv * myv) / (sxx - pcount * (mxv * mxv) + 1e-5f);
    float bb = myv - kk * mxv;
    float tt = 1.0f + kk / (bb + 1e-8f);
    float len = sqrtf(1.0f + kk * kk) * (mxX - mnX);
    bool m = (pcount > 10.0f) && (len > 0.1f) && (kk > -1.0f) && (kk < 0.0f)
             && (tt > 0.01f) && (tt < 0.99f);
    float res = tt * (m ? 1.0f : 0.0f);   // keep JAX NaN*0 semantics
    if (mode == 0) st->tp1[pid] = res; else st->tp2[pid] = res;
  }
}

// ---------- 7: gf pass-1 horizontal + inline V-maxpool + REPLICATED percentile ----------
// The percentile replica reads only tp1/tp2 (8 KB, already loaded into LDS for
// t_fusion) — every block deterministically computes the identical tminbits.
__global__ __launch_bounds__(512) void k_gf1h(const float* __restrict__ img,
                                              const float* __restrict__ mh,
                                              const State* __restrict__ st,
                                              float4* __restrict__ box4) {
  __shared__ float tp1s[NPATCH], tp2s[NPATCH];
  __shared__ float Pl[540], Il[540];
  __shared__ float tbv[480];
  __shared__ unsigned lh[256];
  __shared__ unsigned lds[258];
  int y = blockIdx.x, t = threadIdx.x;
  for (int i = t; i < NPATCH; i += 512) { tp1s[i] = st->tp1[i]; tp2s[i] = st->tp2[i]; }
  // inline V-maxpool + clip for row y (bit-exact vs old k_maxV_pct)
  for (int x = t; x < W; x += 512) {
    float m = -INFINITY;
    for (int d = -7; d <= 7; ++d) {
      int yy = y + d;
      float v = ((unsigned)yy < (unsigned)HT) ? mh[yy * W + x] : 0.0f;
      m = fmaxf(m, v);
    }
    tbv[x] = fminf(fmaxf(m, 0.05f), 1.0f);
  }
  __syncthreads();
  // ---- replicated percentile: 4-level radix select on region areas ----
  unsigned prefix = 0u, k = 11521u;   // 1-based rank of sorted[11520]
  for (int level = 0; level < 4; ++level) {
    if (t < 256) lh[t] = 0u;
    __syncthreads();
    unsigned mask = (level == 0) ? 0u : (0xFFFFFFFFu << (32 - 8 * level));
    int shift = 24 - 8 * level;
    for (int i = t; i < NPATCH; i += 512) {
      int ph = i >> 5, pw = i & 31;
      float a = tp1s[i];
      int rcnt[2], ridx[2], ccnt[2], cidx[2];
      if (ph == 0) { rcnt[0] = 7; ridx[0] = -1; rcnt[1] = 8; ridx[1] = 0; }
      else         { rcnt[0] = 4; ridx[0] = ph - 1; rcnt[1] = 11; ridx[1] = ph; }
      if (pw == 0) { ccnt[0] = 7; cidx[0] = -1; ccnt[1] = 8; cidx[1] = 0; }
      else         { ccnt[0] = 4; cidx[0] = pw - 1; ccnt[1] = 11; cidx[1] = pw; }
      for (int ri = 0; ri < 2; ++ri)
        for (int ci = 0; ci < 2; ++ci) {
          unsigned area = (unsigned)(rcnt[ri] * ccnt[ci]);
          float bb = 0.0f;
          if (ridx[ri] >= 0 && cidx[ci] >= 0) bb = tp2s[ridx[ri] * 32 + cidx[ci]];
          float r;
          if (a != 0.0f && bb != 0.0f) r = (a + bb) / 2.0f;
          else r = (a != 0.0f) ? a : bb;
          float u = (r > 0.0f) ? r : 10.0f;            // where(t>0,t,10); NaN->10
          unsigned bits = __float_as_uint(u);
          if ((bits & mask) == prefix)
            atomicAdd(&lh[(bits >> shift) & 0xFFu], area);
        }
    }
    __syncthreads();
    unsigned ch, kn;
    resolve_level(lh, k, 0, lds, ch, kn);
    prefix |= ch << shift;
    k = kn;
  }
  float tmin = __uint_as_float(prefix);
  // ---- t_fusion + I + horizontal 61-box sums ----
  int c1row = (y / 15) * 32;
  bool c2ok = (y >= 7);
  int c2row = c2ok ? ((y - 4) / 15) * 32 : 0;
  for (int i = t; i < 540; i += 512) {
    int col = i - 30;
    float pv = 0.0f, iv = 0.0f;
    if ((unsigned)col < (unsigned)W) {
      int q = y * W + col;
      float a = tp1s[c1row + col / 15];
      float bb = 0.0f;
      if (c2ok && col >= 7) bb = tp2s[c2row + (col - 4) / 15];
      float r;
      if (a != 0.0f && bb != 0.0f) r = (a + bb) / 2.0f;   // NaN != 0 true, as in JAX
      else r = (a != 0.0f) ? a : bb;
      float v = (r > 0.0f) ? r : tbv[col];                // NaN -> tb
      v = (v < tmin) ? tmin : v;
      v = (v > 1.0f) ? 1.0f : v;
      pv = v;
      iv = ((img[q] + img[HW + q]) + img[2 * HW + q]) / 3.0f;  // I inline, bit-exact
    }
    Pl[i] = pv; Il[i] = iv;
  }
  __syncthreads();
  if (t < W) {
    float sI = 0.f, sP = 0.f, sIp = 0.f, sII = 0.f;
    for (int d = 0; d < 61; ++d) {
      float iv = Il[t + d], pv = Pl[t + d];
      sI += iv; sP += pv; sIp += iv * pv; sII += iv * iv;
    }
    box4[y * W + t] = make_float4(sI, sP, sIp, sII);
  }
}

// ---------- 8: gf pass-1 vertical + pass-2 horizontal, fused per-row ----------
__global__ __launch_bounds__(512) void k_gf1vh(const float4* __restrict__ box4,
                                               float2* __restrict__ hab) {
  __shared__ float2 l[540];
  int y = blockIdx.x, t = threadIdx.x;
  float2 v = make_float2(0.f, 0.f);
  if (t < W) {
    float sI = 0.f, sP = 0.f, sIp = 0.f, sII = 0.f;
    for (int d = -30; d <= 30; ++d) {
      int yy = y + d;
      if ((unsigned)yy < (unsigned)HT) {
        float4 b = box4[yy * W + t];
        sI += b.x; sP += b.y; sIp += b.z; sII += b.w;
      }
    }
    int ny = min(y + 30, HT - 1) - max(y - 30, 0) + 1;
    int nx = min(t + 30, W - 1) - max(t - 30, 0) + 1;
    float Nn = (float)(ny * nx);
    float mI = sI / Nn, mP = sP / Nn, mIp = sIp / Nn, mII = sII / Nn;
    float cov = mIp - mI * mP;
    float var = mII - mI * mI;
    float av = cov / (var + 1e-3f);
    v = make_float2(av, mP - av * mI);
  }
  if (t < 30) { l[t] = make_float2(0.f, 0.f); l[510 + t] = make_float2(0.f, 0.f); }
  if (t < W) l[30 + t] = v;
  __syncthreads();
  if (t < W) {
    float sa = 0.f, sb = 0.f;
    for (int d = 0; d < 61; ++d) { float2 u = l[t + d]; sa += u.x; sb += u.y; }
    hab[y * W + t] = make_float2(sa, sb);
  }
}

// ---------- 9: gf pass-2 vertical + restore epilogue (I inline) ----------
__global__ __launch_bounds__(256) void k_gf2vfin(const float2* __restrict__ hab,
                                                 const float* __restrict__ img,
                                                 const State* __restrict__ st,
                                                 float* __restrict__ out) {
  int p = blockIdx.x * 256 + threadIdx.x;
  int y = p / W, x = p - y * W;
  float sa = 0.f, sb = 0.f;
  for (int d = -30; d <= 30; ++d) {
    int yy = y + d;
    if ((unsigned)yy < (unsigned)HT) { float2 v = hab[yy * W + x]; sa += v.x; sb += v.y; }
  }
  int ny = min(y + 30, HT - 1) - max(y - 30, 0) + 1;
  int nx = min(x + 30, W - 1) - max(x - 30, 0) + 1;
  float Nn = (float)(ny * nx);
  float r = img[p], g = img[HW + p], bl = img[2 * HW + p];
  float Iv = ((r + g) + bl) / 3.0f;                       // I inline, bit-exact
  float tref = (sa / Nn) * Iv + (sb / Nn);
  float A0 = st->A[0], A1 = st->A[1], A2 = st->A[2];
  out[p]          = (r  - A0) / tref + A0;
  out[HW + p]     = (g  - A1) / tref + A1;
  out[2 * HW + p] = (bl - A2) / tref + A2;
}

// ---------- launch: 9 dispatches ----------
extern "C" void kernel_launch(void* const* d_in, const int* in_sizes, int n_in,
                              void* d_out, int out_size, void* d_ws, size_t ws_size,
                              hipStream_t stream) {
  (void)in_sizes; (void)n_in; (void)out_size; (void)ws_size;
  const float* img = (const float*)d_in[0];
  float* out = (float*)d_out;
  State* st = (State*)d_ws;
  unsigned* hist16 = (unsigned*)((char*)d_ws + 65536);      // 256 KB
  float* sb = (float*)((char*)d_ws + 65536 + 262144);
  // layout (floats): A=dc [0,HW) ; B=rowmin->mh [HW,2HW) ;
  // box4 [2HW,6HW) ; hab [6HW,8HW)
  float* bufA = sb;
  float* bufB = sb + HW;
  float4* box4 = (float4*)(sb + 2 * HW);
  float2* hab  = (float2*)(sb + 6 * HW);

  dim3 b256(256), b512(512);
  dim3 ge(NT), rows(HT);

  k_rowmin<<<rows, b512, 0, stream>>>(img, bufB, st, hist16);
  k_minV3<<<ge, b256, 0, stream>>>(bufB, bufA, hist16);           // dc + hist16
  k_resolve16<<<dim3(1), b256, 0, stream>>>(hist16, st);
  k_gather2<<<ge, b256, 0, stream>>>(bufA, img, st);
  k_finalizeA2<<<dim3(1), b256, 0, stream>>>(img, st);
  k_mega1<<<dim3(2048 + HT), b256, 0, stream>>>(img, bufB, st);   // tp1/tp2 + mh
  k_gf1h<<<rows, b512, 0, stream>>>(img, bufB, st, box4);         // maxV + pct + box sums
  k_gf1vh<<<rows, b512, 0, stream>>>(box4, hab);
  k_gf2vfin<<<ge, b256, 0, stream>>>(hab, img, st, out);
}